// Round 1
// baseline (132.814 us; speedup 1.0000x reference)
//
#include <hip/hip_runtime.h>

// Siddon forward projection.
// inputs (dict order): image[4][256][256] f32, tvals[69120][514] f32,
//                      M[2][2] f32, b[2] f32, src[69120][2] f32, dst[69120][2] f32
// output: sinogram[4][69120] f32
//
// One wave (64 lanes) per ray; lanes stride over the 513 segments.

#define N_ROW  256
#define N_COL  256
#define N_RAY  69120
#define NT     514      // tvals per ray
#define NSEG   513
#define NB     4
#define IMG_PIX (N_ROW * N_COL)

__global__ __launch_bounds__(256) void ct_fwd_kernel(
    const float* __restrict__ image,
    const float* __restrict__ tvals,
    const float* __restrict__ Mm,
    const float* __restrict__ bb,
    const float* __restrict__ src,
    const float* __restrict__ dst,
    float* __restrict__ out)
{
    const int wave = (blockIdx.x * blockDim.x + threadIdx.x) >> 6;
    const int lane = threadIdx.x & 63;
    if (wave >= N_RAY) return;
    const int ray = wave;

    // analytic 2x2 inverse of M (wave-uniform scalar loads)
    const float m00 = Mm[0], m01 = Mm[1], m10 = Mm[2], m11 = Mm[3];
    const float invdet = 1.0f / (m00 * m11 - m01 * m10);
    const float i00 =  m11 * invdet, i01 = -m01 * invdet;
    const float i10 = -m10 * invdet, i11 =  m00 * invdet;

    const float sx = src[ray * 2 + 0], sy = src[ray * 2 + 1];
    const float ex = dst[ray * 2 + 0], ey = dst[ray * 2 + 1];
    const float bx = bb[0], by = bb[1];

    // p0 = Minv @ (src - b);  d = Minv @ (dst - src)   (index space)
    const float p0x = i00 * (sx - bx) + i01 * (sy - by);
    const float p0y = i10 * (sx - bx) + i11 * (sy - by);
    const float wdx = ex - sx, wdy = ey - sy;
    const float dx = i00 * wdx + i01 * wdy;
    const float dy = i10 * wdx + i11 * wdy;
    const float ray_len = sqrtf(wdx * wdx + wdy * wdy);

    const float* __restrict__ tv  = tvals + (long)ray * NT;
    const float* __restrict__ im0 = image;
    const float* __restrict__ im1 = image + 1 * IMG_PIX;
    const float* __restrict__ im2 = image + 2 * IMG_PIX;
    const float* __restrict__ im3 = image + 3 * IMG_PIX;

    float acc0 = 0.f, acc1 = 0.f, acc2 = 0.f, acc3 = 0.f;

    #pragma unroll
    for (int i = 0; i < 9; ++i) {
        const int s = i * 64 + lane;
        if (s < NSEG) {
            const float t0 = tv[s];
            const float t1 = tv[s + 1];
            const float dt = t1 - t0;
            if (dt > 0.f) {
                const float tm = 0.5f * (t0 + t1);
                const float ux = fmaf(tm, dx, p0x);
                const float uy = fmaf(tm, dy, p0y);
                const float rf = floorf(ux + 0.5f);
                const float cf = floorf(uy + 0.5f);
                if (rf >= 0.f && rf < (float)N_ROW && cf >= 0.f && cf < (float)N_COL) {
                    const int idx = (int)rf * N_COL + (int)cf;
                    const float w = dt * ray_len;
                    acc0 = fmaf(w, im0[idx], acc0);
                    acc1 = fmaf(w, im1[idx], acc1);
                    acc2 = fmaf(w, im2[idx], acc2);
                    acc3 = fmaf(w, im3[idx], acc3);
                }
            }
        }
    }

    // 64-lane butterfly reduce (4 accumulators)
    #pragma unroll
    for (int off = 32; off >= 1; off >>= 1) {
        acc0 += __shfl_xor(acc0, off);
        acc1 += __shfl_xor(acc1, off);
        acc2 += __shfl_xor(acc2, off);
        acc3 += __shfl_xor(acc3, off);
    }

    if (lane == 0) {
        out[0 * N_RAY + ray] = acc0;
        out[1 * N_RAY + ray] = acc1;
        out[2 * N_RAY + ray] = acc2;
        out[3 * N_RAY + ray] = acc3;
    }
}

extern "C" void kernel_launch(void* const* d_in, const int* in_sizes, int n_in,
                              void* d_out, int out_size, void* d_ws, size_t ws_size,
                              hipStream_t stream) {
    const float* image = (const float*)d_in[0];
    const float* tvals = (const float*)d_in[1];
    const float* Mm    = (const float*)d_in[2];
    const float* bb    = (const float*)d_in[3];
    const float* src   = (const float*)d_in[4];
    const float* dst   = (const float*)d_in[5];
    float* out = (float*)d_out;

    // one wave per ray, 4 waves (256 threads) per block
    const int blocks = N_RAY / 4;   // 69120 / 4 = 17280
    ct_fwd_kernel<<<blocks, 256, 0, stream>>>(image, tvals, Mm, bb, src, dst, out);
}

// Round 2
// 65.844 us; speedup vs baseline: 2.0171x; 2.0171x over previous
//
#include <hip/hip_runtime.h>

// Siddon forward projection, round 2.
// inputs: image[4][256][256] f32, tvals[69120][514] f32, M[2][2], b[2],
//         src[69120][2], dst[69120][2]
// output: sinogram[4][69120] f32
//
// One wave per ray, lanes stride over segments. Image gathers are made
// coalesced by staging a channel-interleaved float4 image in d_ws in BOTH
// orientations (r-major and c-major); each ray picks the orientation whose
// fastest axis matches its dominant direction.

#define N_ROW  256
#define N_COL  256
#define N_RAY  69120
#define NT     514
#define NSEG   513
#define IMG_PIX (N_ROW * N_COL)
#define WS_NEEDED (2u * IMG_PIX * 16u)   // two float4 images = 2 MiB

__global__ __launch_bounds__(256) void ct_prep_kernel(
    const float* __restrict__ image,
    float4* __restrict__ img_rc,   // [r*256 + c] -> (ch0..ch3)
    float4* __restrict__ img_cr)   // [c*256 + r] -> (ch0..ch3)
{
    const int p = blockIdx.x * blockDim.x + threadIdx.x;   // r*256 + c
    if (p >= IMG_PIX) return;
    const int r = p >> 8;
    const int c = p & 255;
    float4 v;
    v.x = image[0 * IMG_PIX + p];
    v.y = image[1 * IMG_PIX + p];
    v.z = image[2 * IMG_PIX + p];
    v.w = image[3 * IMG_PIX + p];
    img_rc[p] = v;
    img_cr[(c << 8) | r] = v;
}

__global__ __launch_bounds__(256) void ct_fwd_kernel(
    const float4* __restrict__ img_rc,
    const float4* __restrict__ img_cr,
    const float* __restrict__ tvals,
    const float* __restrict__ Mm,
    const float* __restrict__ bb,
    const float* __restrict__ src,
    const float* __restrict__ dst,
    float* __restrict__ out)
{
    const int wave = (blockIdx.x * blockDim.x + threadIdx.x) >> 6;
    const int lane = threadIdx.x & 63;
    if (wave >= N_RAY) return;
    const int ray = wave;

    const float m00 = Mm[0], m01 = Mm[1], m10 = Mm[2], m11 = Mm[3];
    const float invdet = 1.0f / (m00 * m11 - m01 * m10);
    const float i00 =  m11 * invdet, i01 = -m01 * invdet;
    const float i10 = -m10 * invdet, i11 =  m00 * invdet;

    const float sx = src[ray * 2 + 0], sy = src[ray * 2 + 1];
    const float ex = dst[ray * 2 + 0], ey = dst[ray * 2 + 1];
    const float bx = bb[0], by = bb[1];

    const float p0x = i00 * (sx - bx) + i01 * (sy - by);
    const float p0y = i10 * (sx - bx) + i11 * (sy - by);
    const float wdx = ex - sx, wdy = ey - sy;
    const float dx = i00 * wdx + i01 * wdy;
    const float dy = i10 * wdx + i11 * wdy;
    const float ray_len = sqrtf(wdx * wdx + wdy * wdy);

    // pick the layout whose fastest-varying axis is the ray's dominant axis:
    // r-dominant ray -> img_cr (idx = c*256 + r, r fastest)
    // c-dominant ray -> img_rc (idx = r*256 + c, c fastest)
    const bool rdom = fabsf(dx) >= fabsf(dy);
    const float4* __restrict__ img = rdom ? img_cr : img_rc;

    const float* __restrict__ tv = tvals + (long)ray * NT;

    float acc0 = 0.f, acc1 = 0.f, acc2 = 0.f, acc3 = 0.f;

    #pragma unroll
    for (int i = 0; i < 9; ++i) {
        const int s = i * 64 + lane;
        if (s < NSEG) {
            const float t0 = tv[s];
            const float t1 = tv[s + 1];
            const float dt = t1 - t0;
            if (dt > 0.f) {
                const float tm = 0.5f * (t0 + t1);
                const float ux = fmaf(tm, dx, p0x);
                const float uy = fmaf(tm, dy, p0y);
                const float rf = floorf(ux + 0.5f);
                const float cf = floorf(uy + 0.5f);
                if (rf >= 0.f && rf < (float)N_ROW && cf >= 0.f && cf < (float)N_COL) {
                    const int r = (int)rf, c = (int)cf;
                    const int idx = rdom ? ((c << 8) | r) : ((r << 8) | c);
                    const float w = dt * ray_len;
                    const float4 v = img[idx];
                    acc0 = fmaf(w, v.x, acc0);
                    acc1 = fmaf(w, v.y, acc1);
                    acc2 = fmaf(w, v.z, acc2);
                    acc3 = fmaf(w, v.w, acc3);
                }
            }
        }
    }

    #pragma unroll
    for (int off = 32; off >= 1; off >>= 1) {
        acc0 += __shfl_xor(acc0, off);
        acc1 += __shfl_xor(acc1, off);
        acc2 += __shfl_xor(acc2, off);
        acc3 += __shfl_xor(acc3, off);
    }

    if (lane == 0) {
        out[0 * N_RAY + ray] = acc0;
        out[1 * N_RAY + ray] = acc1;
        out[2 * N_RAY + ray] = acc2;
        out[3 * N_RAY + ray] = acc3;
    }
}

// ---- legacy fallback (round-1 kernel) if ws is too small ----
__global__ __launch_bounds__(256) void ct_fwd_legacy(
    const float* __restrict__ image,
    const float* __restrict__ tvals,
    const float* __restrict__ Mm,
    const float* __restrict__ bb,
    const float* __restrict__ src,
    const float* __restrict__ dst,
    float* __restrict__ out)
{
    const int wave = (blockIdx.x * blockDim.x + threadIdx.x) >> 6;
    const int lane = threadIdx.x & 63;
    if (wave >= N_RAY) return;
    const int ray = wave;

    const float m00 = Mm[0], m01 = Mm[1], m10 = Mm[2], m11 = Mm[3];
    const float invdet = 1.0f / (m00 * m11 - m01 * m10);
    const float i00 =  m11 * invdet, i01 = -m01 * invdet;
    const float i10 = -m10 * invdet, i11 =  m00 * invdet;

    const float sx = src[ray * 2 + 0], sy = src[ray * 2 + 1];
    const float ex = dst[ray * 2 + 0], ey = dst[ray * 2 + 1];
    const float bx = bb[0], by = bb[1];

    const float p0x = i00 * (sx - bx) + i01 * (sy - by);
    const float p0y = i10 * (sx - bx) + i11 * (sy - by);
    const float wdx = ex - sx, wdy = ey - sy;
    const float dx = i00 * wdx + i01 * wdy;
    const float dy = i10 * wdx + i11 * wdy;
    const float ray_len = sqrtf(wdx * wdx + wdy * wdy);

    const float* __restrict__ tv  = tvals + (long)ray * NT;
    const float* __restrict__ im0 = image;
    const float* __restrict__ im1 = image + 1 * IMG_PIX;
    const float* __restrict__ im2 = image + 2 * IMG_PIX;
    const float* __restrict__ im3 = image + 3 * IMG_PIX;

    float acc0 = 0.f, acc1 = 0.f, acc2 = 0.f, acc3 = 0.f;

    #pragma unroll
    for (int i = 0; i < 9; ++i) {
        const int s = i * 64 + lane;
        if (s < NSEG) {
            const float t0 = tv[s];
            const float t1 = tv[s + 1];
            const float dt = t1 - t0;
            if (dt > 0.f) {
                const float tm = 0.5f * (t0 + t1);
                const float ux = fmaf(tm, dx, p0x);
                const float uy = fmaf(tm, dy, p0y);
                const float rf = floorf(ux + 0.5f);
                const float cf = floorf(uy + 0.5f);
                if (rf >= 0.f && rf < (float)N_ROW && cf >= 0.f && cf < (float)N_COL) {
                    const int idx = (int)rf * N_COL + (int)cf;
                    const float w = dt * ray_len;
                    acc0 = fmaf(w, im0[idx], acc0);
                    acc1 = fmaf(w, im1[idx], acc1);
                    acc2 = fmaf(w, im2[idx], acc2);
                    acc3 = fmaf(w, im3[idx], acc3);
                }
            }
        }
    }

    #pragma unroll
    for (int off = 32; off >= 1; off >>= 1) {
        acc0 += __shfl_xor(acc0, off);
        acc1 += __shfl_xor(acc1, off);
        acc2 += __shfl_xor(acc2, off);
        acc3 += __shfl_xor(acc3, off);
    }

    if (lane == 0) {
        out[0 * N_RAY + ray] = acc0;
        out[1 * N_RAY + ray] = acc1;
        out[2 * N_RAY + ray] = acc2;
        out[3 * N_RAY + ray] = acc3;
    }
}

extern "C" void kernel_launch(void* const* d_in, const int* in_sizes, int n_in,
                              void* d_out, int out_size, void* d_ws, size_t ws_size,
                              hipStream_t stream) {
    const float* image = (const float*)d_in[0];
    const float* tvals = (const float*)d_in[1];
    const float* Mm    = (const float*)d_in[2];
    const float* bb    = (const float*)d_in[3];
    const float* src   = (const float*)d_in[4];
    const float* dst   = (const float*)d_in[5];
    float* out = (float*)d_out;

    const int blocks = N_RAY / 4;   // 4 waves (4 rays) per 256-thread block

    if (ws_size >= WS_NEEDED) {
        float4* img_rc = (float4*)d_ws;
        float4* img_cr = img_rc + IMG_PIX;
        ct_prep_kernel<<<IMG_PIX / 256, 256, 0, stream>>>(image, img_rc, img_cr);
        ct_fwd_kernel<<<blocks, 256, 0, stream>>>(img_rc, img_cr, tvals, Mm, bb,
                                                  src, dst, out);
    } else {
        ct_fwd_legacy<<<blocks, 256, 0, stream>>>(image, tvals, Mm, bb,
                                                  src, dst, out);
    }
}

// Round 3
// 48.620 us; speedup vs baseline: 2.7317x; 1.3543x over previous
//
#include <hip/hip_runtime.h>

// Siddon forward projection, round 3: analytic chunked DDA (no tvals read).
// inputs: image[4][256][256] f32, tvals[69120][514] f32 (UNUSED), M[2][2],
//         b[2], src[69120][2], dst[69120][2]
// output: sinogram[4][69120] f32
//
// One thread per (ray, chunk): the ray's slab range [t_in,t_out] is split
// into 8 equal t-chunks; each thread DDA-marches its chunk with closed-form
// crossing times. Chunk boundaries split segments into parts with identical
// midpoint pixels, so the partition is exact. Width-8 shuffle reduce.

#define N_ROW  256
#define N_COL  256
#define N_RAY  69120
#define IMG_PIX (N_ROW * N_COL)
#define PCHUNK 8
#define MAXIT  72
#define WS_NEEDED (2u * IMG_PIX * 16u)   // two float4 images = 2 MiB

__global__ __launch_bounds__(256) void ct_prep_kernel(
    const float* __restrict__ image,
    float4* __restrict__ img_rc,   // [r*256 + c] -> (ch0..ch3), c fastest
    float4* __restrict__ img_cr)   // [c*256 + r] -> (ch0..ch3), r fastest
{
    const int p = blockIdx.x * blockDim.x + threadIdx.x;
    if (p >= IMG_PIX) return;
    const int r = p >> 8;
    const int c = p & 255;
    float4 v;
    v.x = image[0 * IMG_PIX + p];
    v.y = image[1 * IMG_PIX + p];
    v.z = image[2 * IMG_PIX + p];
    v.w = image[3 * IMG_PIX + p];
    img_rc[p] = v;
    img_cr[(c << 8) | r] = v;
}

__global__ __launch_bounds__(256) void ct_dda_kernel(
    const float4* __restrict__ img_rc,
    const float4* __restrict__ img_cr,
    const float* __restrict__ Mm,
    const float* __restrict__ bb,
    const float* __restrict__ src,
    const float* __restrict__ dst,
    float* __restrict__ out)
{
    const int tid = blockIdx.x * blockDim.x + threadIdx.x;
    const int ray = tid >> 3;       // 8 chunks per ray
    const int k   = tid & 7;
    if (ray >= N_RAY) return;

    // analytic 2x2 inverse of M (wave-uniform)
    const float m00 = Mm[0], m01 = Mm[1], m10 = Mm[2], m11 = Mm[3];
    const float invdet = 1.0f / (m00 * m11 - m01 * m10);
    const float i00 =  m11 * invdet, i01 = -m01 * invdet;
    const float i10 = -m10 * invdet, i11 =  m00 * invdet;

    const float sx = src[ray * 2 + 0], sy = src[ray * 2 + 1];
    const float ex = dst[ray * 2 + 0], ey = dst[ray * 2 + 1];
    const float bx = bb[0], by = bb[1];

    const float p0x = i00 * (sx - bx) + i01 * (sy - by);
    const float p0y = i10 * (sx - bx) + i11 * (sy - by);
    const float wdx = ex - sx, wdy = ey - sy;
    const float dxo = i00 * wdx + i01 * wdy;
    const float dyo = i10 * wdx + i11 * wdy;
    const float len = sqrtf(wdx * wdx + wdy * wdy);

    const float EPS = 1e-12f;
    const float dx = (fabsf(dxo) < EPS) ? EPS : dxo;   // matches reference d_safe
    const float dy = (fabsf(dyo) < EPS) ? EPS : dyo;
    const float ivx = 1.0f / dx;
    const float ivy = 1.0f / dy;

    // slab intersection with [0,1]
    const float tx0 = (-0.5f  - p0x) * ivx, tx1 = (255.5f - p0x) * ivx;
    const float ty0 = (-0.5f  - p0y) * ivy, ty1 = (255.5f - p0y) * ivy;
    const float txmin = fminf(tx0, tx1), txmax = fmaxf(tx0, tx1);
    const float tymin = fminf(ty0, ty1), tymax = fmaxf(ty0, ty1);
    const float t_in  = fmaxf(fmaxf(txmin, tymin), 0.0f);
    const float t_out = fminf(fminf(txmax, tymax), 1.0f);
    const float span  = fmaxf(t_out - t_in, 0.0f);

    // this thread's t-chunk (eighths are exact in fp -> boundaries match)
    float tcur     = t_in + span * ((float)k       * 0.125f);
    const float tb = t_in + span * ((float)(k + 1) * 0.125f);

    // closed-form init of next-crossing state at tcur
    const float xpos = fmaf(tcur, dx, p0x);
    float px; int r;
    if (dx > 0.0f) { const float f = floorf(xpos + 0.5f);        r = (int)f; px = f + 0.5f; }
    else           { const float f = ceilf (xpos + 0.5f) - 1.0f; r = (int)f; px = f - 0.5f; }
    float trx = (px - p0x) * ivx;

    const float ypos = fmaf(tcur, dy, p0y);
    float py; int c;
    if (dy > 0.0f) { const float f = floorf(ypos + 0.5f);        c = (int)f; py = f + 0.5f; }
    else           { const float f = ceilf (ypos + 0.5f) - 1.0f; c = (int)f; py = f - 0.5f; }
    float tcy = (py - p0y) * ivy;

    const float srx = (dx > 0.0f) ?  1.0f : -1.0f;
    const int   sri = (dx > 0.0f) ?  1    : -1;
    const float sry = (dy > 0.0f) ?  1.0f : -1.0f;
    const int   sci = (dy > 0.0f) ?  1    : -1;

    // gather layout: fastest axis = perpendicular-dominant axis
    // (8 lanes of a wave cluster = 8 adjacent detectors, 1 px apart along perp)
    const bool rdom = fabsf(dx) >= fabsf(dy);
    const float4* __restrict__ img = rdom ? img_rc : img_cr;

    float a0 = 0.f, a1 = 0.f, a2 = 0.f, a3 = 0.f;

    for (int it = 0; it < MAXIT; ++it) {
        const float tn = fminf(fminf(trx, tcy), tb);
        const float dt = tn - tcur;
        const int rc = min(max(r, 0), 255);   // insurance clamp (dt~0 at edges)
        const int cc = min(max(c, 0), 255);
        const int idx = rdom ? ((rc << 8) | cc) : ((cc << 8) | rc);
        const float w = dt * len;
        const float4 v = img[idx];
        a0 = fmaf(w, v.x, a0);
        a1 = fmaf(w, v.y, a1);
        a2 = fmaf(w, v.z, a2);
        a3 = fmaf(w, v.w, a3);
        if (tn >= tb) break;
        if (trx <= tcy) { r += sri; px += srx; trx = (px - p0x) * ivx; }
        else            { c += sci; py += sry; tcy = (py - p0y) * ivy; }
        tcur = tn;
    }

    // width-8 reduce over chunks (groups aligned to 8 lanes)
    #pragma unroll
    for (int off = 4; off >= 1; off >>= 1) {
        a0 += __shfl_xor(a0, off);
        a1 += __shfl_xor(a1, off);
        a2 += __shfl_xor(a2, off);
        a3 += __shfl_xor(a3, off);
    }

    if (k == 0) {
        out[0 * N_RAY + ray] = a0;
        out[1 * N_RAY + ray] = a1;
        out[2 * N_RAY + ray] = a2;
        out[3 * N_RAY + ray] = a3;
    }
}

// ---- legacy fallback (round-1 kernel) if ws is too small ----
__global__ __launch_bounds__(256) void ct_fwd_legacy(
    const float* __restrict__ image,
    const float* __restrict__ tvals,
    const float* __restrict__ Mm,
    const float* __restrict__ bb,
    const float* __restrict__ src,
    const float* __restrict__ dst,
    float* __restrict__ out)
{
    const int wave = (blockIdx.x * blockDim.x + threadIdx.x) >> 6;
    const int lane = threadIdx.x & 63;
    if (wave >= N_RAY) return;
    const int ray = wave;

    const float m00 = Mm[0], m01 = Mm[1], m10 = Mm[2], m11 = Mm[3];
    const float invdet = 1.0f / (m00 * m11 - m01 * m10);
    const float i00 =  m11 * invdet, i01 = -m01 * invdet;
    const float i10 = -m10 * invdet, i11 =  m00 * invdet;

    const float sx = src[ray * 2 + 0], sy = src[ray * 2 + 1];
    const float ex = dst[ray * 2 + 0], ey = dst[ray * 2 + 1];
    const float bx = bb[0], by = bb[1];

    const float p0x = i00 * (sx - bx) + i01 * (sy - by);
    const float p0y = i10 * (sx - bx) + i11 * (sy - by);
    const float wdx = ex - sx, wdy = ey - sy;
    const float dx = i00 * wdx + i01 * wdy;
    const float dy = i10 * wdx + i11 * wdy;
    const float ray_len = sqrtf(wdx * wdx + wdy * wdy);

    const float* __restrict__ tv  = tvals + (long)ray * 514;
    const float* __restrict__ im0 = image;
    const float* __restrict__ im1 = image + 1 * IMG_PIX;
    const float* __restrict__ im2 = image + 2 * IMG_PIX;
    const float* __restrict__ im3 = image + 3 * IMG_PIX;

    float acc0 = 0.f, acc1 = 0.f, acc2 = 0.f, acc3 = 0.f;

    #pragma unroll
    for (int i = 0; i < 9; ++i) {
        const int s = i * 64 + lane;
        if (s < 513) {
            const float t0 = tv[s];
            const float t1 = tv[s + 1];
            const float dt = t1 - t0;
            if (dt > 0.f) {
                const float tm = 0.5f * (t0 + t1);
                const float ux = fmaf(tm, dx, p0x);
                const float uy = fmaf(tm, dy, p0y);
                const float rf = floorf(ux + 0.5f);
                const float cf = floorf(uy + 0.5f);
                if (rf >= 0.f && rf < (float)N_ROW && cf >= 0.f && cf < (float)N_COL) {
                    const int idx = (int)rf * N_COL + (int)cf;
                    const float w = dt * ray_len;
                    acc0 = fmaf(w, im0[idx], acc0);
                    acc1 = fmaf(w, im1[idx], acc1);
                    acc2 = fmaf(w, im2[idx], acc2);
                    acc3 = fmaf(w, im3[idx], acc3);
                }
            }
        }
    }

    #pragma unroll
    for (int off = 32; off >= 1; off >>= 1) {
        acc0 += __shfl_xor(acc0, off);
        acc1 += __shfl_xor(acc1, off);
        acc2 += __shfl_xor(acc2, off);
        acc3 += __shfl_xor(acc3, off);
    }

    if (lane == 0) {
        out[0 * N_RAY + ray] = acc0;
        out[1 * N_RAY + ray] = acc1;
        out[2 * N_RAY + ray] = acc2;
        out[3 * N_RAY + ray] = acc3;
    }
}

extern "C" void kernel_launch(void* const* d_in, const int* in_sizes, int n_in,
                              void* d_out, int out_size, void* d_ws, size_t ws_size,
                              hipStream_t stream) {
    const float* image = (const float*)d_in[0];
    const float* tvals = (const float*)d_in[1];
    const float* Mm    = (const float*)d_in[2];
    const float* bb    = (const float*)d_in[3];
    const float* src   = (const float*)d_in[4];
    const float* dst   = (const float*)d_in[5];
    float* out = (float*)d_out;

    if (ws_size >= WS_NEEDED) {
        float4* img_rc = (float4*)d_ws;
        float4* img_cr = img_rc + IMG_PIX;
        ct_prep_kernel<<<IMG_PIX / 256, 256, 0, stream>>>(image, img_rc, img_cr);
        const int nthreads = N_RAY * PCHUNK;            // 552960
        ct_dda_kernel<<<nthreads / 256, 256, 0, stream>>>(img_rc, img_cr, Mm, bb,
                                                          src, dst, out);
    } else {
        ct_fwd_legacy<<<N_RAY / 4, 256, 0, stream>>>(image, tvals, Mm, bb,
                                                     src, dst, out);
    }
}

// Round 4
// 40.345 us; speedup vs baseline: 3.2920x; 1.2051x over previous
//
#include <hip/hip_runtime.h>

// Siddon forward projection, round 4: analytic chunked DDA, 4-crossing
// batched inner loop (4 gathers in flight per wave).
// inputs: image[4][256][256] f32, tvals[69120][514] f32 (UNUSED), M[2][2],
//         b[2], src[69120][2], dst[69120][2]
// output: sinogram[4][69120] f32

#define N_ROW  256
#define N_COL  256
#define N_RAY  69120
#define IMG_PIX (N_ROW * N_COL)
#define PCHUNK 8
#define NBATCH 20          // 20 * 4 = 80 steps max per chunk (worst case ~67)
#define WS_NEEDED (2u * IMG_PIX * 16u)   // two float4 images = 2 MiB

__global__ __launch_bounds__(256) void ct_prep_kernel(
    const float* __restrict__ image,
    float4* __restrict__ img_rc,   // [r*256 + c] -> (ch0..ch3), c fastest
    float4* __restrict__ img_cr)   // [c*256 + r] -> (ch0..ch3), r fastest
{
    const int p = blockIdx.x * blockDim.x + threadIdx.x;
    if (p >= IMG_PIX) return;
    const int r = p >> 8;
    const int c = p & 255;
    float4 v;
    v.x = image[0 * IMG_PIX + p];
    v.y = image[1 * IMG_PIX + p];
    v.z = image[2 * IMG_PIX + p];
    v.w = image[3 * IMG_PIX + p];
    img_rc[p] = v;
    img_cr[(c << 8) | r] = v;
}

__global__ __launch_bounds__(256) void ct_dda_kernel(
    const float4* __restrict__ img_rc,
    const float4* __restrict__ img_cr,
    const float* __restrict__ Mm,
    const float* __restrict__ bb,
    const float* __restrict__ src,
    const float* __restrict__ dst,
    float* __restrict__ out)
{
    const int tid = blockIdx.x * blockDim.x + threadIdx.x;
    const int ray = tid >> 3;       // 8 chunks per ray
    const int k   = tid & 7;
    if (ray >= N_RAY) return;

    // analytic 2x2 inverse of M (wave-uniform)
    const float m00 = Mm[0], m01 = Mm[1], m10 = Mm[2], m11 = Mm[3];
    const float invdet = 1.0f / (m00 * m11 - m01 * m10);
    const float i00 =  m11 * invdet, i01 = -m01 * invdet;
    const float i10 = -m10 * invdet, i11 =  m00 * invdet;

    const float sx = src[ray * 2 + 0], sy = src[ray * 2 + 1];
    const float ex = dst[ray * 2 + 0], ey = dst[ray * 2 + 1];
    const float bx = bb[0], by = bb[1];

    const float p0x = i00 * (sx - bx) + i01 * (sy - by);
    const float p0y = i10 * (sx - bx) + i11 * (sy - by);
    const float wdx = ex - sx, wdy = ey - sy;
    const float dxo = i00 * wdx + i01 * wdy;
    const float dyo = i10 * wdx + i11 * wdy;
    const float len = sqrtf(wdx * wdx + wdy * wdy);

    const float EPS = 1e-12f;
    const float dx = (fabsf(dxo) < EPS) ? EPS : dxo;
    const float dy = (fabsf(dyo) < EPS) ? EPS : dyo;
    const float ivx = 1.0f / dx;
    const float ivy = 1.0f / dy;

    // slab intersection with [0,1]
    const float tx0 = (-0.5f  - p0x) * ivx, tx1 = (255.5f - p0x) * ivx;
    const float ty0 = (-0.5f  - p0y) * ivy, ty1 = (255.5f - p0y) * ivy;
    const float txmin = fminf(tx0, tx1), txmax = fmaxf(tx0, tx1);
    const float tymin = fminf(ty0, ty1), tymax = fmaxf(ty0, ty1);
    const float t_in  = fmaxf(fmaxf(txmin, tymin), 0.0f);
    const float t_out = fminf(fminf(txmax, tymax), 1.0f);
    const float span  = fmaxf(t_out - t_in, 0.0f);

    // this thread's t-chunk (identical formula across neighbors -> exact split)
    const float tcur0 = t_in + span * ((float)k       * 0.125f);
    const float tb0   = t_in + span * ((float)(k + 1) * 0.125f);

    // closed-form init of next-crossing state at tcur0
    const float xpos = fmaf(tcur0, dx, p0x);
    float pxf; int r;
    if (dx > 0.0f) { const float f = floorf(xpos + 0.5f);        r = (int)f; pxf = f + 0.5f; }
    else           { const float f = ceilf (xpos + 0.5f) - 1.0f; r = (int)f; pxf = f - 0.5f; }

    const float ypos = fmaf(tcur0, dy, p0y);
    float pyf; int c;
    if (dy > 0.0f) { const float f = floorf(ypos + 0.5f);        c = (int)f; pyf = f + 0.5f; }
    else           { const float f = ceilf (ypos + 0.5f) - 1.0f; c = (int)f; pyf = f - 0.5f; }

    const int sri = (dx > 0.0f) ? 1 : -1;
    const int sci = (dy > 0.0f) ? 1 : -1;

    // times scaled by ray length: weights come out directly as (T1 - T0)
    float Trx = ((pxf - p0x) * ivx) * len;
    float Tcy = ((pyf - p0y) * ivy) * len;
    const float advx = fabsf(ivx) * len;
    const float advy = fabsf(ivy) * len;
    float Tc = tcur0 * len;
    const float Tb = tb0 * len;

    // gather layout: fastest axis = perpendicular-dominant axis
    const bool rdom = fabsf(dx) >= fabsf(dy);
    const float4* __restrict__ img = rdom ? img_rc : img_cr;

    float a0 = 0.f, a1 = 0.f, a2 = 0.f, a3 = 0.f;

    for (int bIt = 0; bIt < NBATCH; ++bIt) {
        if (Tc >= Tb) break;
        int   idxv[4];
        float wv[4];
        #pragma unroll
        for (int j = 0; j < 4; ++j) {
            const float tn = fminf(fminf(Trx, Tcy), Tb);
            wv[j] = tn - Tc;                       // >= 0; 0 once chunk is done
            const int rc = min(max(r, 0), 255);
            const int cc = min(max(c, 0), 255);
            idxv[j] = rdom ? ((rc << 8) | cc) : ((cc << 8) | rc);
            const bool xstep = (Trx <= Tcy);
            r   += xstep ? sri  : 0;
            c   += xstep ? 0    : sci;
            Trx += xstep ? advx : 0.0f;
            Tcy += xstep ? 0.0f : advy;
            Tc = tn;
        }
        const float4 v0 = img[idxv[0]];
        const float4 v1 = img[idxv[1]];
        const float4 v2 = img[idxv[2]];
        const float4 v3 = img[idxv[3]];
        a0 = fmaf(wv[0], v0.x, a0); a1 = fmaf(wv[0], v0.y, a1);
        a2 = fmaf(wv[0], v0.z, a2); a3 = fmaf(wv[0], v0.w, a3);
        a0 = fmaf(wv[1], v1.x, a0); a1 = fmaf(wv[1], v1.y, a1);
        a2 = fmaf(wv[1], v1.z, a2); a3 = fmaf(wv[1], v1.w, a3);
        a0 = fmaf(wv[2], v2.x, a0); a1 = fmaf(wv[2], v2.y, a1);
        a2 = fmaf(wv[2], v2.z, a2); a3 = fmaf(wv[2], v2.w, a3);
        a0 = fmaf(wv[3], v3.x, a0); a1 = fmaf(wv[3], v3.y, a1);
        a2 = fmaf(wv[3], v3.z, a2); a3 = fmaf(wv[3], v3.w, a3);
    }

    // width-8 reduce over chunks (groups aligned to 8 lanes)
    #pragma unroll
    for (int off = 4; off >= 1; off >>= 1) {
        a0 += __shfl_xor(a0, off);
        a1 += __shfl_xor(a1, off);
        a2 += __shfl_xor(a2, off);
        a3 += __shfl_xor(a3, off);
    }

    if (k == 0) {
        out[0 * N_RAY + ray] = a0;
        out[1 * N_RAY + ray] = a1;
        out[2 * N_RAY + ray] = a2;
        out[3 * N_RAY + ray] = a3;
    }
}

// ---- legacy fallback (round-1 kernel) if ws is too small ----
__global__ __launch_bounds__(256) void ct_fwd_legacy(
    const float* __restrict__ image,
    const float* __restrict__ tvals,
    const float* __restrict__ Mm,
    const float* __restrict__ bb,
    const float* __restrict__ src,
    const float* __restrict__ dst,
    float* __restrict__ out)
{
    const int wave = (blockIdx.x * blockDim.x + threadIdx.x) >> 6;
    const int lane = threadIdx.x & 63;
    if (wave >= N_RAY) return;
    const int ray = wave;

    const float m00 = Mm[0], m01 = Mm[1], m10 = Mm[2], m11 = Mm[3];
    const float invdet = 1.0f / (m00 * m11 - m01 * m10);
    const float i00 =  m11 * invdet, i01 = -m01 * invdet;
    const float i10 = -m10 * invdet, i11 =  m00 * invdet;

    const float sx = src[ray * 2 + 0], sy = src[ray * 2 + 1];
    const float ex = dst[ray * 2 + 0], ey = dst[ray * 2 + 1];
    const float bx = bb[0], by = bb[1];

    const float p0x = i00 * (sx - bx) + i01 * (sy - by);
    const float p0y = i10 * (sx - bx) + i11 * (sy - by);
    const float wdx = ex - sx, wdy = ey - sy;
    const float dx = i00 * wdx + i01 * wdy;
    const float dy = i10 * wdx + i11 * wdy;
    const float ray_len = sqrtf(wdx * wdx + wdy * wdy);

    const float* __restrict__ tv  = tvals + (long)ray * 514;
    const float* __restrict__ im0 = image;
    const float* __restrict__ im1 = image + 1 * IMG_PIX;
    const float* __restrict__ im2 = image + 2 * IMG_PIX;
    const float* __restrict__ im3 = image + 3 * IMG_PIX;

    float acc0 = 0.f, acc1 = 0.f, acc2 = 0.f, acc3 = 0.f;

    #pragma unroll
    for (int i = 0; i < 9; ++i) {
        const int s = i * 64 + lane;
        if (s < 513) {
            const float t0 = tv[s];
            const float t1 = tv[s + 1];
            const float dt = t1 - t0;
            if (dt > 0.f) {
                const float tm = 0.5f * (t0 + t1);
                const float ux = fmaf(tm, dx, p0x);
                const float uy = fmaf(tm, dy, p0y);
                const float rf = floorf(ux + 0.5f);
                const float cf = floorf(uy + 0.5f);
                if (rf >= 0.f && rf < (float)N_ROW && cf >= 0.f && cf < (float)N_COL) {
                    const int idx = (int)rf * N_COL + (int)cf;
                    const float w = dt * ray_len;
                    acc0 = fmaf(w, im0[idx], acc0);
                    acc1 = fmaf(w, im1[idx], acc1);
                    acc2 = fmaf(w, im2[idx], acc2);
                    acc3 = fmaf(w, im3[idx], acc3);
                }
            }
        }
    }

    #pragma unroll
    for (int off = 32; off >= 1; off >>= 1) {
        acc0 += __shfl_xor(acc0, off);
        acc1 += __shfl_xor(acc1, off);
        acc2 += __shfl_xor(acc2, off);
        acc3 += __shfl_xor(acc3, off);
    }

    if (lane == 0) {
        out[0 * N_RAY + ray] = acc0;
        out[1 * N_RAY + ray] = acc1;
        out[2 * N_RAY + ray] = acc2;
        out[3 * N_RAY + ray] = acc3;
    }
}

extern "C" void kernel_launch(void* const* d_in, const int* in_sizes, int n_in,
                              void* d_out, int out_size, void* d_ws, size_t ws_size,
                              hipStream_t stream) {
    const float* image = (const float*)d_in[0];
    const float* tvals = (const float*)d_in[1];
    const float* Mm    = (const float*)d_in[2];
    const float* bb    = (const float*)d_in[3];
    const float* src   = (const float*)d_in[4];
    const float* dst   = (const float*)d_in[5];
    float* out = (float*)d_out;

    if (ws_size >= WS_NEEDED) {
        float4* img_rc = (float4*)d_ws;
        float4* img_cr = img_rc + IMG_PIX;
        ct_prep_kernel<<<IMG_PIX / 256, 256, 0, stream>>>(image, img_rc, img_cr);
        const int nthreads = N_RAY * PCHUNK;            // 552960
        ct_dda_kernel<<<nthreads / 256, 256, 0, stream>>>(img_rc, img_cr, Mm, bb,
                                                          src, dst, out);
    } else {
        ct_fwd_legacy<<<N_RAY / 4, 256, 0, stream>>>(image, tvals, Mm, bb,
                                                     src, dst, out);
    }
}